// Round 7
// baseline (103.772 us; speedup 1.0000x reference)
//
#include <hip/hip_runtime.h>

#define NQ 10

struct cplx { float x, y; };
__device__ __forceinline__ cplx mk(float x, float y){ cplx c; c.x=x; c.y=y; return c; }

// ===== cross-lane xor-exchange: DPP (VALU pipe) for masks 1,2,8; DS otherwise =====
// xor1 = quad_perm [1,0,3,2] = 0xB1 ; xor2 = quad_perm [2,3,0,1] = 0x4E
// xor8 = row_ror:8 = 0x128  ((i+8)%16 == i^8 within a 16-lane row)
template<int M>
__device__ __forceinline__ float lxf(float v){
    if constexpr (M == 1 || M == 2 || M == 8) {
        constexpr int ctrl = (M == 1) ? 0xB1 : (M == 2) ? 0x4E : 0x128;
        return __int_as_float(__builtin_amdgcn_update_dpp(
            0, __float_as_int(v), ctrl, 0xF, 0xF, true));
    } else {
        return __shfl_xor(v, M, 64);
    }
}
template<int M>
__device__ __forceinline__ cplx lxc(cplx a){
    cplx r; r.x = lxf<M>(a.x); r.y = lxf<M>(a.y); return r;
}

// ===== Rot gate, wire in reg bits: full pair update =====
template<int M, int R>
__device__ __forceinline__ void rot_reg(cplx (&a)[16],
        float u00x,float u00y,float u01x,float u01y,
        float u10x,float u10y,float u11x,float u11y){
    if constexpr (R < 16) {
        if constexpr ((R & M) == 0) {
            cplx a0 = a[R], a1 = a[R|M];
            a[R].x   = u00x*a0.x - u00y*a0.y + u01x*a1.x - u01y*a1.y;
            a[R].y   = u00x*a0.y + u00y*a0.x + u01x*a1.y + u01y*a1.x;
            a[R|M].x = u10x*a0.x - u10y*a0.y + u11x*a1.x - u11y*a1.y;
            a[R|M].y = u10x*a0.y + u10y*a0.x + u11x*a1.y + u11y*a1.x;
        }
        rot_reg<M,R+1>(a, u00x,u00y,u01x,u01y,u10x,u10y,u11x,u11y);
    }
}

// ===== Rot gate, wire in lane bits: coefficients pre-selected by caller =====
template<int LM, int R>
__device__ __forceinline__ void rot_lane(cplx (&a)[16],
        float uax,float uay,float ubx,float uby){
    if constexpr (R < 16) {
        cplx p = lxc<LM>(a[R]);
        cplx m = a[R];
        a[R].x = uax*m.x - uay*m.y + ubx*p.x - uby*p.y;
        a[R].y = uax*m.y + uay*m.x + ubx*p.y + uby*p.x;
        rot_lane<LM,R+1>(a, uax,uay,ubx,uby);
    }
}

// ===== CRX(pi/3): symmetric pair op  n = al*mine - i*be*partner =====

template<int MC, int MT, int R>
__device__ __forceinline__ void crx_rr(cplx (&a)[16], float cc, float ss){
    if constexpr (R < 16) {
        if constexpr ((R & MC) != 0 && (R & MT) == 0) {
            cplx a0 = a[R], a1 = a[R|MT];
            a[R].x    = cc*a0.x + ss*a1.y;  a[R].y    = cc*a0.y - ss*a1.x;
            a[R|MT].x = cc*a1.x + ss*a0.y;  a[R|MT].y = cc*a1.y - ss*a0.x;
        }
        crx_rr<MC,MT,R+1>(a, cc, ss);
    }
}

template<int MC, int LM, int R>
__device__ __forceinline__ void crx_rl(cplx (&a)[16], float cc, float ss){
    if constexpr (R < 16) {
        if constexpr ((R & MC) != 0) {
            cplx p = lxc<LM>(a[R]);
            cplx m = a[R];
            a[R].x = cc*m.x + ss*p.y;
            a[R].y = cc*m.y - ss*p.x;
        }
        crx_rl<MC,LM,R+1>(a, cc, ss);
    }
}

template<int MT, int R>
__device__ __forceinline__ void crx_lr(cplx (&a)[16], float al, float be){
    if constexpr (R < 16) {
        if constexpr ((R & MT) == 0) {
            cplx a0 = a[R], a1 = a[R|MT];
            a[R].x    = al*a0.x + be*a1.y;  a[R].y    = al*a0.y - be*a1.x;
            a[R|MT].x = al*a1.x + be*a0.y;  a[R|MT].y = al*a1.y - be*a0.x;
        }
        crx_lr<MT,R+1>(a, al, be);
    }
}

template<int TLM, int R>
__device__ __forceinline__ void crx_ll(cplx (&a)[16], float al, float be){
    if constexpr (R < 16) {
        cplx p = lxc<TLM>(a[R]);
        cplx m = a[R];
        a[R].x = al*m.x + be*p.y;
        a[R].y = al*m.y - be*p.x;
        crx_ll<TLM,R+1>(a, al, be);
    }
}

// ===== JIT Rot gate (RZ(omega) elided: commutes to the CNOT cascade = basis
// permutation, vanishes under |.|^2.  Rot -> RY(th)RZ(phi)) =====
template<int I>
__device__ __forceinline__ void do_rot(cplx (&amp)[16], int lane, const float* __restrict__ w){
    float phi = w[I*3 + 0], th = w[I*3 + 1];
    float ct, st, cp, sp;
    __sincosf(0.5f * th,  &st, &ct);
    __sincosf(0.5f * phi, &sp, &cp);
    float A = ct*cp, Bv = ct*sp, C = st*cp, D = st*sp;
    // u00=(A,-B) u01=(-C,-D) u10=(C,-D) u11=(A,B)
    if constexpr (I < 4) {
        rot_reg<(1<<I),0>(amp, A,-Bv, -C,-D, C,-D, A,Bv);
    } else {
        constexpr int LM = 1 << (I - 4);
        const bool hi = (lane & LM) != 0;
        float uax = A,            uay = hi ? Bv : -Bv;  // hi?u11:u00
        float ubx = hi ? C : -C,  uby = -D;             // hi?u10:u01
        rot_lane<LM,0>(amp, uax,uay,ubx,uby);
    }
}

// ===== measurement: 4 signed sums, CNOT cascade folded into parity masks =====
template<int R>
__device__ __forceinline__ void accum4(const cplx (&a)[16], float &SA, float &SB, float &SC, float &SD){
    if constexpr (R < 16) {
        float p = a[R].x*a[R].x + a[R].y*a[R].y;
        SA += ((R>>2) & 1)            ? -p : p;
        SB += ((R>>3) & 1)            ? -p : p;
        SC += ((R ^ (R>>2)) & 1)      ? -p : p;
        SD += (((R>>1) ^ (R>>3)) & 1) ? -p : p;
        accum4<R+1>(a, SA, SB, SC, SD);
    }
}

__device__ __forceinline__ float wave_sum(float v){
    v += lxf< 1>(v);
    v += lxf< 2>(v);
    v += lxf< 4>(v);
    v += lxf< 8>(v);
    v += lxf<16>(v);
    v += lxf<32>(v);
    return v;
}

// 64-point Walsh-Hadamard over lanes: output lane l = sum_j (-1)^{popcount(j&l)} x_j
__device__ __forceinline__ float wht64(float v, int lane){
    float p;
    p = lxf< 1>(v); v = (lane &  1) ? p - v : v + p;
    p = lxf< 2>(v); v = (lane &  2) ? p - v : v + p;
    p = lxf< 4>(v); v = (lane &  4) ? p - v : v + p;
    p = lxf< 8>(v); v = (lane &  8) ? p - v : v + p;
    p = lxf<16>(v); v = (lane & 16) ? p - v : v + p;
    p = lxf<32>(v); v = (lane & 32) ? p - v : v + p;
    return v;
}

__device__ __forceinline__ float fsgn(float v, unsigned s){
    return __uint_as_float(__float_as_uint(v) ^ s);
}
__device__ __forceinline__ unsigned parsgn(int lane, int m){
    return (unsigned)((__builtin_popcount(lane & m) & 1)) << 31;
}

// (256,4): VGPR cap 128; working set ~50 so cap is never binding (no round-4-style spill).
__global__ __launch_bounds__(256, 4) void qsim_kernel(const float* __restrict__ inputs,
                                                      const float* __restrict__ weights,
                                                      float* __restrict__ out, int B){
    const int lane = threadIdx.x & 63;
    const int wave = __builtin_amdgcn_readfirstlane((int)((blockIdx.x * blockDim.x + threadIdx.x) >> 6));
    if (wave >= B) return;

    const float* ang = inputs + (size_t)wave * NQ;

    // ---- lane-qubit factor F, one sincos live at a time ----
    float F = 1.f;
    {
        float s, c;
        __sincosf(0.5f * ang[4], &s, &c); F *= (lane &  1) ? s : c;
        __sincosf(0.5f * ang[5], &s, &c); F *= (lane &  2) ? s : c;
        __sincosf(0.5f * ang[6], &s, &c); F *= (lane &  4) ? s : c;
        __sincosf(0.5f * ang[7], &s, &c); F *= (lane &  8) ? s : c;
        __sincosf(0.5f * ang[8], &s, &c); F *= (lane & 16) ? s : c;
        __sincosf(0.5f * ang[9], &s, &c); F *= (lane & 32) ? s : c;
    }

    // ---- reg-qubit product state ----
    float c0,s0,c1,s1,c2,s2,c3,s3;
    __sincosf(0.5f * ang[0], &s0, &c0);
    __sincosf(0.5f * ang[1], &s1, &c1);
    __sincosf(0.5f * ang[2], &s2, &c2);
    __sincosf(0.5f * ang[3], &s3, &c3);

    float v2a = F * c0, v2b = F * s0;
    float v4[4] = { v2a*c1, v2b*c1, v2a*s1, v2b*s1 };
    float v8[8] = { v4[0]*c2, v4[1]*c2, v4[2]*c2, v4[3]*c2,
                    v4[0]*s2, v4[1]*s2, v4[2]*s2, v4[3]*s2 };

    cplx amp[16];
    #pragma unroll
    for (int r = 0; r < 8; ++r) {
        amp[r]   = mk(v8[r] * c3, 0.f);
        amp[r+8] = mk(v8[r] * s3, 0.f);
    }

    // ---- CRX(pi/3) over chain edges (EDGES order) ----
    const float cc = 0.86602540378443864676f;  // cos(pi/6)
    const float ss = 0.5f;                     // sin(pi/6)
    crx_rr<1, 2, 0>(amp, cc, ss);                                    // (0,1)
    crx_rr<2, 4, 0>(amp, cc, ss);                                    // (1,2)
    crx_rr<4, 8, 0>(amp, cc, ss);                                    // (2,3)
    crx_rl<8, 1, 0>(amp, cc, ss);                                    // (3,4)  xor1 -> DPP
    { bool t = (lane &  1); crx_ll< 2,0>(amp, t?cc:1.f, t?ss:0.f); } // (4,5)  xor2 -> DPP
    { bool t = (lane &  2); crx_ll< 4,0>(amp, t?cc:1.f, t?ss:0.f); } // (5,6)  xor4 -> DS
    { bool t = (lane &  4); crx_ll< 8,0>(amp, t?cc:1.f, t?ss:0.f); } // (6,7)  xor8 -> DPP
    { bool t = (lane &  8); crx_ll<16,0>(amp, t?cc:1.f, t?ss:0.f); } // (7,8)  xor16 -> DS
    { bool t = (lane & 16); crx_ll<32,0>(amp, t?cc:1.f, t?ss:0.f); } // (8,9)  xor32 -> DS
    { bool t = (lane & 32); crx_lr< 1,0>(amp, t?cc:1.f, t?ss:0.f); } // (9,0)  no shuffle

    // ---- StronglyEntanglingLayers Rot gates (RZ(omega) elided) ----
    do_rot<0>(amp, lane, weights);
    do_rot<1>(amp, lane, weights);
    do_rot<2>(amp, lane, weights);
    do_rot<3>(amp, lane, weights);
    do_rot<4>(amp, lane, weights);
    do_rot<5>(amp, lane, weights);
    do_rot<6>(amp, lane, weights);
    do_rot<7>(amp, lane, weights);
    do_rot<8>(amp, lane, weights);
    do_rot<9>(amp, lane, weights);

    // ---- measurement: CNOT cascade folded into parity masks ----
    // <Z_w> needs signed sums over x=(lane<<4)|r with reg-sign in {SA,SB,SC,SD}
    // and lane-masks: r0:(SA,21) r1:(SB,42) r2..r8 even: (SC, 0/1/5/21),
    // r3..r9 odd: (SD, 0/2/10/42).  WHT gives the whole SC/SD families at once:
    // lane l of wht64(SC) = mask-l signed sum.
    float SA = 0.f, SB = 0.f, SC = 0.f, SD = 0.f;
    accum4<0>(amp, SA, SB, SC, SD);

    float r0  = wave_sum(fsgn(SA, parsgn(lane, 21)));
    float r1  = wave_sum(fsgn(SB, parsgn(lane, 42)));
    float wsc = wht64(SC, lane);
    float wsd = wht64(SD, lane);

    float* o = out + (size_t)wave * NQ;
    if (lane == 0)       { o[0] = r0; o[1] = r1; o[2] = wsc; o[3] = wsd; }
    else if (lane == 1)  o[4] = wsc;
    else if (lane == 5)  o[6] = wsc;
    else if (lane == 21) o[8] = wsc;
    if (lane == 2)       o[5] = wsd;
    else if (lane == 10) o[7] = wsd;
    else if (lane == 42) o[9] = wsd;
}

extern "C" void kernel_launch(void* const* d_in, const int* in_sizes, int n_in,
                              void* d_out, int out_size, void* d_ws, size_t ws_size,
                              hipStream_t stream) {
    const float* inputs  = (const float*)d_in[0];   // (B, 10) float32
    const float* weights = (const float*)d_in[1];   // (1, 10, 3) float32
    float* out = (float*)d_out;                     // (B, 10) float32
    const int B = in_sizes[0] / NQ;
    const int wavesPerBlock = 256 / 64;
    const int blocks = (B + wavesPerBlock - 1) / wavesPerBlock;
    qsim_kernel<<<blocks, 256, 0, stream>>>(inputs, weights, out, B);
}

// Round 9
// 79.203 us; speedup vs baseline: 1.3102x; 1.3102x over previous
//
#include <hip/hip_runtime.h>

#define NQ 10

typedef float f32x2 __attribute__((ext_vector_type(2)));
struct cplx2 { f32x2 x, y; };  // .x/.y = real/imag; each f32x2 = (sample0, sample1)

// ===== cross-lane xor-exchange =====
// masks 1,2,8: single DPP (quad_perm 0xB1 / 0x4E, row_ror:8) — VALU pipe
// mask 4: 2x DPP (row_shl:4 / row_shr:4) + select — VALU pipe
//   lane with bit2=0 wants v[l+4]: row_shl:4, valid since l%16 in {0..3,8..11} < 12
//   lane with bit2=1 wants v[l-4]: row_shr:4, valid since l%16 in {4..7,12..15} >= 4
// masks 16,32: DS shfl_xor (permlane*_swap failed correctness in R8 — do not use)
template<int M>
__device__ __forceinline__ float lxf(float v){
    if constexpr (M == 1 || M == 2 || M == 8) {
        constexpr int ctrl = (M == 1) ? 0xB1 : (M == 2) ? 0x4E : 0x128;
        return __int_as_float(__builtin_amdgcn_update_dpp(
            0, __float_as_int(v), ctrl, 0xF, 0xF, true));
    } else if constexpr (M == 4) {
        float up = __int_as_float(__builtin_amdgcn_update_dpp(
            0, __float_as_int(v), 0x104, 0xF, 0xF, true));  // row_shl:4 -> v[l+4]
        float dn = __int_as_float(__builtin_amdgcn_update_dpp(
            0, __float_as_int(v), 0x114, 0xF, 0xF, true));  // row_shr:4 -> v[l-4]
        return (threadIdx.x & 4) ? dn : up;
    } else {
        return __shfl_xor(v, M, 64);
    }
}
template<int M>
__device__ __forceinline__ f32x2 lx2(f32x2 v){
    f32x2 r; r.x = lxf<M>(v.x); r.y = lxf<M>(v.y); return r;
}
template<int M>
__device__ __forceinline__ cplx2 lxc(cplx2 a){
    cplx2 r; r.x = lx2<M>(a.x); r.y = lx2<M>(a.y); return r;
}

// ===== Rot gate, wire in reg bits: full pair update =====
template<int M, int R>
__device__ __forceinline__ void rot_reg(cplx2 (&a)[16],
        float u00x,float u00y,float u01x,float u01y,
        float u10x,float u10y,float u11x,float u11y){
    if constexpr (R < 16) {
        if constexpr ((R & M) == 0) {
            cplx2 a0 = a[R], a1 = a[R|M];
            a[R].x   = u00x*a0.x - u00y*a0.y + u01x*a1.x - u01y*a1.y;
            a[R].y   = u00x*a0.y + u00y*a0.x + u01x*a1.y + u01y*a1.x;
            a[R|M].x = u10x*a0.x - u10y*a0.y + u11x*a1.x - u11y*a1.y;
            a[R|M].y = u10x*a0.y + u10y*a0.x + u11x*a1.y + u11y*a1.x;
        }
        rot_reg<M,R+1>(a, u00x,u00y,u01x,u01y,u10x,u10y,u11x,u11y);
    }
}

// ===== Rot gate, wire in lane bits: coefficients pre-selected by caller =====
template<int LM, int R>
__device__ __forceinline__ void rot_lane(cplx2 (&a)[16],
        float uax,float uay,float ubx,float uby){
    if constexpr (R < 16) {
        cplx2 p = lxc<LM>(a[R]);
        cplx2 m = a[R];
        a[R].x = uax*m.x - uay*m.y + ubx*p.x - uby*p.y;
        a[R].y = uax*m.y + uay*m.x + ubx*p.y + uby*p.x;
        rot_lane<LM,R+1>(a, uax,uay,ubx,uby);
    }
}

// ===== CRX(pi/3): symmetric pair op  n = al*mine - i*be*partner =====

template<int MC, int MT, int R>
__device__ __forceinline__ void crx_rr(cplx2 (&a)[16], float cc, float ss){
    if constexpr (R < 16) {
        if constexpr ((R & MC) != 0 && (R & MT) == 0) {
            cplx2 a0 = a[R], a1 = a[R|MT];
            a[R].x    = cc*a0.x + ss*a1.y;  a[R].y    = cc*a0.y - ss*a1.x;
            a[R|MT].x = cc*a1.x + ss*a0.y;  a[R|MT].y = cc*a1.y - ss*a0.x;
        }
        crx_rr<MC,MT,R+1>(a, cc, ss);
    }
}

template<int MC, int LM, int R>
__device__ __forceinline__ void crx_rl(cplx2 (&a)[16], float cc, float ss){
    if constexpr (R < 16) {
        if constexpr ((R & MC) != 0) {
            cplx2 p = lxc<LM>(a[R]);
            cplx2 m = a[R];
            a[R].x = cc*m.x + ss*p.y;
            a[R].y = cc*m.y - ss*p.x;
        }
        crx_rl<MC,LM,R+1>(a, cc, ss);
    }
}

template<int MT, int R>
__device__ __forceinline__ void crx_lr(cplx2 (&a)[16], float al, float be){
    if constexpr (R < 16) {
        if constexpr ((R & MT) == 0) {
            cplx2 a0 = a[R], a1 = a[R|MT];
            a[R].x    = al*a0.x + be*a1.y;  a[R].y    = al*a0.y - be*a1.x;
            a[R|MT].x = al*a1.x + be*a0.y;  a[R|MT].y = al*a1.y - be*a0.x;
        }
        crx_lr<MT,R+1>(a, al, be);
    }
}

template<int TLM, int R>
__device__ __forceinline__ void crx_ll(cplx2 (&a)[16], float al, float be){
    if constexpr (R < 16) {
        cplx2 p = lxc<TLM>(a[R]);
        cplx2 m = a[R];
        a[R].x = al*m.x + be*p.y;
        a[R].y = al*m.y - be*p.x;
        crx_ll<TLM,R+1>(a, al, be);
    }
}

// ===== JIT Rot gate (RZ(omega) elided: commutes to the CNOT cascade = basis
// permutation, vanishes under |.|^2.  Rot -> RY(th)RZ(phi)) =====
template<int I>
__device__ __forceinline__ void do_rot(cplx2 (&amp)[16], int lane, const float* __restrict__ w){
    float phi = w[I*3 + 0], th = w[I*3 + 1];
    float ct, st, cp, sp;
    __sincosf(0.5f * th,  &st, &ct);
    __sincosf(0.5f * phi, &sp, &cp);
    float A = ct*cp, Bv = ct*sp, C = st*cp, D = st*sp;
    // u00=(A,-B) u01=(-C,-D) u10=(C,-D) u11=(A,B)
    if constexpr (I < 4) {
        rot_reg<(1<<I),0>(amp, A,-Bv, -C,-D, C,-D, A,Bv);
    } else {
        constexpr int LM = 1 << (I - 4);
        const bool hi = (lane & LM) != 0;
        float uax = A,            uay = hi ? Bv : -Bv;  // hi?u11:u00
        float ubx = hi ? C : -C,  uby = -D;             // hi?u10:u01
        rot_lane<LM,0>(amp, uax,uay,ubx,uby);
    }
}

// ===== measurement: 4 signed sums, CNOT cascade folded into parity masks =====
template<int R>
__device__ __forceinline__ void accum4(const cplx2 (&a)[16], f32x2 &SA, f32x2 &SB, f32x2 &SC, f32x2 &SD){
    if constexpr (R < 16) {
        f32x2 p = a[R].x*a[R].x + a[R].y*a[R].y;
        SA += ((R>>2) & 1)            ? -p : p;
        SB += ((R>>3) & 1)            ? -p : p;
        SC += ((R ^ (R>>2)) & 1)      ? -p : p;
        SD += (((R>>1) ^ (R>>3)) & 1) ? -p : p;
        accum4<R+1>(a, SA, SB, SC, SD);
    }
}

__device__ __forceinline__ f32x2 wave_sum2(f32x2 v){
    v += lx2< 1>(v);
    v += lx2< 2>(v);
    v += lx2< 4>(v);
    v += lx2< 8>(v);
    v += lx2<16>(v);
    v += lx2<32>(v);
    return v;
}

// 64-point Walsh-Hadamard over lanes: output lane l = sum_j (-1)^{popcount(j&l)} x_j
__device__ __forceinline__ f32x2 wht2(f32x2 v, int lane){
    f32x2 p;
    p = lx2< 1>(v); v = (lane &  1) ? p - v : v + p;
    p = lx2< 2>(v); v = (lane &  2) ? p - v : v + p;
    p = lx2< 4>(v); v = (lane &  4) ? p - v : v + p;
    p = lx2< 8>(v); v = (lane &  8) ? p - v : v + p;
    p = lx2<16>(v); v = (lane & 16) ? p - v : v + p;
    p = lx2<32>(v); v = (lane & 32) ? p - v : v + p;
    return v;
}

__device__ __forceinline__ f32x2 fsgn2(f32x2 v, unsigned s){
    f32x2 r;
    r.x = __uint_as_float(__float_as_uint(v.x) ^ s);
    r.y = __uint_as_float(__float_as_uint(v.y) ^ s);
    return r;
}
__device__ __forceinline__ unsigned parsgn(int lane, int m){
    return (unsigned)((__builtin_popcount(lane & m) & 1)) << 31;
}

// (256,4): VGPR cap 128 — cplx2 working set ~90-110, proven no-spill regime (R5/R6).
__global__ __launch_bounds__(256, 4) void qsim_kernel(const float* __restrict__ inputs,
                                                      const float* __restrict__ weights,
                                                      float* __restrict__ out, int B, int nPairs){
    const int lane = threadIdx.x & 63;
    const int pair = __builtin_amdgcn_readfirstlane((int)((blockIdx.x * blockDim.x + threadIdx.x) >> 6));
    if (pair >= nPairs) return;

    const int s0 = 2 * pair;
    const int s1 = (s0 + 1 < B) ? s0 + 1 : s0;   // tail-safe load index
    const float* ang0 = inputs + (size_t)s0 * NQ;
    const float* ang1 = inputs + (size_t)s1 * NQ;

    // ---- lane-qubit factor F (per sample), one sincos live at a time ----
    f32x2 F = 1.f;
    #pragma unroll
    for (int w = 4; w < NQ; ++w) {
        float sA, cA, sB, cB;
        __sincosf(0.5f * ang0[w], &sA, &cA);
        __sincosf(0.5f * ang1[w], &sB, &cB);
        bool hi = (lane & (1 << (w - 4))) != 0;
        f32x2 f; f.x = hi ? sA : cA; f.y = hi ? sB : cB;
        F *= f;
    }

    // ---- reg-qubit product state ----
    f32x2 c[4], s[4];
    #pragma unroll
    for (int w = 0; w < 4; ++w) {
        float sA, cA, sB, cB;
        __sincosf(0.5f * ang0[w], &sA, &cA);
        __sincosf(0.5f * ang1[w], &sB, &cB);
        c[w].x = cA; c[w].y = cB; s[w].x = sA; s[w].y = sB;
    }

    f32x2 v2a = F * c[0], v2b = F * s[0];
    f32x2 v4[4] = { v2a*c[1], v2b*c[1], v2a*s[1], v2b*s[1] };
    f32x2 v8[8] = { v4[0]*c[2], v4[1]*c[2], v4[2]*c[2], v4[3]*c[2],
                    v4[0]*s[2], v4[1]*s[2], v4[2]*s[2], v4[3]*s[2] };

    cplx2 amp[16];
    #pragma unroll
    for (int r = 0; r < 8; ++r) {
        amp[r].x   = v8[r] * c[3]; amp[r].y   = 0.f;
        amp[r+8].x = v8[r] * s[3]; amp[r+8].y = 0.f;
    }

    // ---- CRX(pi/3) over chain edges (EDGES order) ----
    const float cc = 0.86602540378443864676f;  // cos(pi/6)
    const float ss = 0.5f;                     // sin(pi/6)
    crx_rr<1, 2, 0>(amp, cc, ss);                                    // (0,1)
    crx_rr<2, 4, 0>(amp, cc, ss);                                    // (1,2)
    crx_rr<4, 8, 0>(amp, cc, ss);                                    // (2,3)
    crx_rl<8, 1, 0>(amp, cc, ss);                                    // (3,4)  xor1 -> DPP
    { bool t = (lane &  1); crx_ll< 2,0>(amp, t?cc:1.f, t?ss:0.f); } // (4,5)  xor2 -> DPP
    { bool t = (lane &  2); crx_ll< 4,0>(amp, t?cc:1.f, t?ss:0.f); } // (5,6)  xor4 -> 2xDPP
    { bool t = (lane &  4); crx_ll< 8,0>(amp, t?cc:1.f, t?ss:0.f); } // (6,7)  xor8 -> DPP
    { bool t = (lane &  8); crx_ll<16,0>(amp, t?cc:1.f, t?ss:0.f); } // (7,8)  xor16 -> DS
    { bool t = (lane & 16); crx_ll<32,0>(amp, t?cc:1.f, t?ss:0.f); } // (8,9)  xor32 -> DS
    { bool t = (lane & 32); crx_lr< 1,0>(amp, t?cc:1.f, t?ss:0.f); } // (9,0)  no shuffle

    // ---- StronglyEntanglingLayers Rot gates (RZ(omega) elided) ----
    do_rot<0>(amp, lane, weights);
    do_rot<1>(amp, lane, weights);
    do_rot<2>(amp, lane, weights);
    do_rot<3>(amp, lane, weights);
    do_rot<4>(amp, lane, weights);
    do_rot<5>(amp, lane, weights);
    do_rot<6>(amp, lane, weights);
    do_rot<7>(amp, lane, weights);
    do_rot<8>(amp, lane, weights);
    do_rot<9>(amp, lane, weights);

    // ---- measurement: CNOT cascade folded into parity masks ----
    // Outputs: o0:(SA,21) o1:(SB,42); SC family masks {0,1,5,21} -> o{2,4,6,8};
    // SD family masks {0,2,10,42} -> o{3,5,7,9}.  WHT lane l = mask-l signed sum.
    f32x2 SA = 0.f, SB = 0.f, SC = 0.f, SD = 0.f;
    accum4<0>(amp, SA, SB, SC, SD);

    f32x2 r0  = wave_sum2(fsgn2(SA, parsgn(lane, 21)));
    f32x2 r1  = wave_sum2(fsgn2(SB, parsgn(lane, 42)));
    f32x2 wsc = wht2(SC, lane);
    f32x2 wsd = wht2(SD, lane);

    float* o0 = out + (size_t)s0 * NQ;
    const bool has1 = (s0 + 1 < B);
    float* o1 = out + (size_t)(s0 + 1) * NQ;

    if (lane == 0) {
        o0[0] = r0.x; o0[1] = r1.x; o0[2] = wsc.x; o0[3] = wsd.x;
        if (has1) { o1[0] = r0.y; o1[1] = r1.y; o1[2] = wsc.y; o1[3] = wsd.y; }
    } else if (lane == 1) {
        o0[4] = wsc.x; if (has1) o1[4] = wsc.y;
    } else if (lane == 5) {
        o0[6] = wsc.x; if (has1) o1[6] = wsc.y;
    } else if (lane == 21) {
        o0[8] = wsc.x; if (has1) o1[8] = wsc.y;
    } else if (lane == 2) {
        o0[5] = wsd.x; if (has1) o1[5] = wsd.y;
    } else if (lane == 10) {
        o0[7] = wsd.x; if (has1) o1[7] = wsd.y;
    } else if (lane == 42) {
        o0[9] = wsd.x; if (has1) o1[9] = wsd.y;
    }
}

extern "C" void kernel_launch(void* const* d_in, const int* in_sizes, int n_in,
                              void* d_out, int out_size, void* d_ws, size_t ws_size,
                              hipStream_t stream) {
    const float* inputs  = (const float*)d_in[0];   // (B, 10) float32
    const float* weights = (const float*)d_in[1];   // (1, 10, 3) float32
    float* out = (float*)d_out;                     // (B, 10) float32
    const int B = in_sizes[0] / NQ;
    const int nPairs = (B + 1) / 2;                 // one wave per 2 samples
    const int wavesPerBlock = 256 / 64;
    const int blocks = (nPairs + wavesPerBlock - 1) / wavesPerBlock;
    qsim_kernel<<<blocks, 256, 0, stream>>>(inputs, weights, out, B, nPairs);
}